// Round 9
// baseline (269.515 us; speedup 1.0000x reference)
//
#include <hip/hip_runtime.h>
#include <hip/hip_fp16.h>
#include <math.h>

#define NNODES 50000
#define NEDGES 800000
#define D 128
#define NPB 8            // nodes per fused block (8 waves, 512 threads)
#define TROWS 72         // token rows: 0-7 self, 8-71 aggregates
#define TS 136           // LDS row stride (halfs): 272 B
#define OS 132           // oo row stride (floats)
#define CAP 64           // bucket capacity per (node,set): Poisson(16), P(>64) ~ 1e-20
#define NBINS 196        // coarse bins of 256 nodes (dst >> 8)
#define BSTRIDE 4608     // arena records per bin: Poisson(4096) + 8 sigma
#define EPB1 4096        // edges per phase-1 block
#define P1PS ((NEDGES + EPB1 - 1) / EPB1)   // 196 phase-1 blocks per set
// kernel-A streaming slot map (after the 392 phase-1 scatter blocks):
//   [0, 2048)        w_swz   : q weight tiles (w_in rows 0-127)
//   [2048, 4096)     wkT_swz : Wk^T per-head A-frags for the Y GEMM
//   [4096, 12288)    wo_swz  : W2_h per-head fused output weights
//   [12288, 12416)   b2      : w_out @ vb + b_out
//   [12416, ...)     x16     : x -> fp16
#define WSWZ_SLOTS 2048
#define WKT_BASE 2048
#define WO_BASE 4096
#define B2_BASE 12288
#define X16_BASE 12416
#define PREP_SLOTS (X16_BASE + NNODES * D / 4)
#define PREP_BLOCKS ((PREP_SLOTS + 255) / 256)

typedef _Float16 half_t;
typedef half_t half2v __attribute__((ext_vector_type(2)));
typedef half_t half4 __attribute__((ext_vector_type(4)));
typedef half_t half8 __attribute__((ext_vector_type(8)));
typedef float floatx4 __attribute__((ext_vector_type(4)));
typedef unsigned short ushort_t;

// Round-9: (a) streaming blocks moved INTO the phase-1 kernel (they are
// independent of the scatter -> overlap instead of serialize; kernel B is now
// 392 pure phase-2 blocks); (b) fused gather prefetches BOTH rounds of BOTH
// sets up front (16 uint4 in flight) -- P(c>16)=0.43 made the second round a
// serial ~500cy stall for half the waves. launch_bounds(512,4) (VGPR cap 128)
// guarantees no scratch spill (round-1 failure mode; falsifier = WRITE_SIZE).
// Algebra (rounds 3/6, verified): scores via y_h = Wk_h^T q_h; output via
// W2_h = w_out_h @ vw, Z[h,:] = attn[h,:] @ tok, b2 = w_out @ vb + b_out.

// ---- kernel A: phase-1 binning (392 blocks) + streaming ----

__global__ __launch_bounds__(256) void prep1_kernel(
    const int* __restrict__ ei0, const int* __restrict__ ei1,
    int* __restrict__ cursor, unsigned int* __restrict__ arena,
    const float* __restrict__ w_in, const float* __restrict__ w_out,
    const float* __restrict__ b_in, const float* __restrict__ b_out,
    const float* __restrict__ x,
    half_t* __restrict__ w_swz, half_t* __restrict__ wkT_swz,
    half_t* __restrict__ wo_swz,
    float* __restrict__ b2, half_t* __restrict__ x16) {
  const int t = threadIdx.x;
  const int b = blockIdx.x;
  if (b < 2 * P1PS) {  // phase-1 binning
    __shared__ int hist[256], cur[256], baseA[256];
    const int set = (b >= P1PS);
    const int blk = set ? (b - P1PS) : b;
    const int* ei = set ? ei1 : ei0;
    hist[t] = 0; cur[t] = 0;
    __syncthreads();
    int dd[16], ss[16];
#pragma unroll
    for (int g = 0; g < 4; ++g) {
      int e = blk * EPB1 + g * 1024 + t * 4;
      if (e < NEDGES) {  // NEDGES % 4 == 0 -> int4 safe
        int4 dv = *(const int4*)(ei + NEDGES + e);
        int4 sv = *(const int4*)(ei + e);
        dd[g * 4 + 0] = dv.x; dd[g * 4 + 1] = dv.y;
        dd[g * 4 + 2] = dv.z; dd[g * 4 + 3] = dv.w;
        ss[g * 4 + 0] = sv.x; ss[g * 4 + 1] = sv.y;
        ss[g * 4 + 2] = sv.z; ss[g * 4 + 3] = sv.w;
      } else {
        dd[g * 4 + 0] = -1; dd[g * 4 + 1] = -1; dd[g * 4 + 2] = -1; dd[g * 4 + 3] = -1;
        ss[g * 4 + 0] = 0;  ss[g * 4 + 1] = 0;  ss[g * 4 + 2] = 0;  ss[g * 4 + 3] = 0;
      }
    }
#pragma unroll
    for (int i = 0; i < 16; ++i)
      if (dd[i] >= 0) atomicAdd(&hist[dd[i] >> 8], 1);
    __syncthreads();
    if (t < NBINS) {  // per-(block,bin) arena reservation: the ONLY device atomics
      int h = hist[t];
      baseA[t] = h ? atomicAdd(&cursor[set * NBINS + t], h) : 0;
    }
    __syncthreads();
#pragma unroll
    for (int i = 0; i < 16; ++i) {
      if (dd[i] >= 0) {
        int bin = dd[i] >> 8;
        int pos = atomicAdd(&cur[bin], 1) + baseA[bin];
        if (pos < BSTRIDE)
          arena[(size_t)(set * NBINS + bin) * BSTRIDE + pos] =
              ((unsigned)(dd[i] & 255) << 16) | (unsigned)ss[i];
      }
    }
    return;
  }
  int slot = (b - 2 * P1PS) * 256 + t;
  if (slot < WSWZ_SLOTS) {  // q weight tiles (w_in rows 0-127)
    int c = slot >> 6, l = slot & 63;
    int nt = c >> 2, ks = c & 3;
    int n = nt * 16 + (l & 15);
    int kb = ks * 32 + (l >> 4) * 8;
    half_t* dst = w_swz + (size_t)slot * 8;
#pragma unroll
    for (int j = 0; j < 8; ++j) dst[j] = (half_t)w_in[n * 128 + kb + j];
  } else if (slot < WO_BASE) {  // Wk^T per-head A-frags: chunk c2 = mt*4 + h
    int s2 = slot - WKT_BASE;       // 0..2047
    int c2 = s2 >> 6, l = s2 & 63;  // chunk 0..31
    int mt = c2 >> 2, h = c2 & 3;
    int m = mt * 16 + (l & 15);
    int j0 = (l >> 4) * 8;
    half_t* dst = wkT_swz + (size_t)s2 * 8;
#pragma unroll
    for (int j = 0; j < 8; ++j)
      dst[j] = (half_t)w_in[(size_t)(128 + h * 32 + j0 + j) * 128 + m];
  } else if (slot < B2_BASE) {  // W2_h, swizzled; K-chunks c2 = nt*16 + ksc
    int s2 = slot - WO_BASE;
    int c2 = s2 >> 6, l = s2 & 63;
    int nt = c2 >> 4, ksc = c2 & 15;
    int n = nt * 16 + (l & 15);
    int h = ksc >> 2;
    int kb = (ksc & 3) * 32 + (l >> 4) * 8;
    float acc[8] = {0.f, 0.f, 0.f, 0.f, 0.f, 0.f, 0.f, 0.f};
    for (int jj = 0; jj < 32; ++jj) {  // jp = h*32 + jj
      float wo = w_out[n * 128 + h * 32 + jj];
      const float* wr = w_in + (size_t)(256 + h * 32 + jj) * 128 + kb;
#pragma unroll
      for (int j = 0; j < 8; ++j) acc[j] = fmaf(wo, wr[j], acc[j]);
    }
    half_t* dst = wo_swz + (size_t)s2 * 8;
#pragma unroll
    for (int j = 0; j < 8; ++j) dst[j] = (half_t)acc[j];
  } else if (slot < X16_BASE) {  // b2 = w_out @ vb + b_out
    int i = slot - B2_BASE;
    float acc = b_out[i];
    for (int j = 0; j < 128; ++j) acc = fmaf(w_out[i * 128 + j], b_in[256 + j], acc);
    b2[i] = acc;
  } else {
    int idx = slot - X16_BASE;
    if (idx < NNODES * D / 4) {
      float4 v = ((const float4*)x)[idx];
      union { half_t h[4]; uint2 u64; } p;
      p.h[0] = (half_t)v.x; p.h[1] = (half_t)v.y;
      p.h[2] = (half_t)v.z; p.h[3] = (half_t)v.w;
      ((uint2*)x16)[idx] = p.u64;
    }
  }
}

// ---- kernel B: phase-2 fine bucketing only (392 blocks) ----

__global__ __launch_bounds__(256) void prep2_kernel(
    const int* __restrict__ cursor, const unsigned int* __restrict__ arena,
    int* __restrict__ cnt0, int* __restrict__ cnt1,
    ushort_t* __restrict__ A0, ushort_t* __restrict__ A1) {
  __shared__ int cntL[256];
  const int t = threadIdx.x;
  const int b = blockIdx.x;
  int set = (b >= NBINS);
  int bin = set ? (b - NBINS) : b;
  cntL[t] = 0;
  __syncthreads();
  int T = cursor[set * NBINS + bin];
  T = T > BSTRIDE ? BSTRIDE : T;
  ushort_t* A = set ? A1 : A0;
  int* cnt = set ? cnt1 : cnt0;
  const unsigned* arn = arena + (size_t)(set * NBINS + bin) * BSTRIDE;
  for (int i = t; i < T; i += 256) {
    unsigned rec = arn[i];
    int r = (rec >> 16) & 0xFF;
    int pos = atomicAdd(&cntL[r], 1);  // LDS atomic — fine counting is free
    if (pos < CAP)
      A[(size_t)(bin * 256 + r) * CAP + pos] = (ushort_t)(rec & 0xFFFF);
  }
  __syncthreads();
  int idx = bin * 256 + t;
  if (idx < NNODES) cnt[idx] = cntL[t] > CAP ? CAP : cntL[t];
}

// ---- fused gather + q proj + Y GEMM + MFMA scores + softmax + Z + W2 GEMM + LN ----
// Round-8 structure; gather now prefetches rounds 0+1 of both sets (16 uint4
// in flight). launch_bounds(512,4): VGPR cap 128 — prefetch must NOT spill
// (round-1 lesson: spill costs 3x, mild occupancy loss costs ~5%).

__global__ __launch_bounds__(512, 4) void fused_attn_kernel(
    const half_t* __restrict__ x16,
    const int* __restrict__ cnt0, const ushort_t* __restrict__ A0,
    const int* __restrict__ cnt1, const ushort_t* __restrict__ A1,
    const half_t* __restrict__ w_swz, const half_t* __restrict__ wkT_swz,
    const half_t* __restrict__ wo_swz,
    const float* __restrict__ b_in, const float* __restrict__ b2,
    const float* __restrict__ gamma, const float* __restrict__ beta,
    float* __restrict__ out) {
  __shared__ half_t tokS[TROWS * TS];  // 19584 B; oo fp32 aliases rows 0-15 post-Z
  __shared__ half_t qS[8 * TS];        // 2176 B: q of node r at row r
  __shared__ half_t yzS[32 * TS];      // 8704 B: Y rows n*4+h, overwritten by Z
  __shared__ float scS[NPB][4][9];     // 1152 B
  __shared__ int cntS[NPB][2];         // 64 B

  const int tid = threadIdx.x;
  const int lane = tid & 63, wv = tid >> 6;
  const int quad = lane >> 4, l15 = lane & 15;
  const int slot = quad;      // gather row slot 0..3
  const int d16 = l15;        // gather dim block (8 dims)
  const int node = blockIdx.x * NPB + wv;
  const int node_s = __builtin_amdgcn_readfirstlane(node);  // wave-uniform -> s_load

  // --- counts + bucket entries (contiguous 128 B/node; counts pre-clamped <=64) ---
  int c0 = cnt0[node_s];
  int c1 = cnt1[node_s];
  if (lane == 0) { cntS[wv][0] = c0; cntS[wv][1] = c1; }
  int ent0 = A0[(size_t)node_s * CAP + lane];  // lanes >= c0 read garbage, never selected
  int ent1 = A1[(size_t)node_s * CAP + lane];
  uint selfw = ((const uint*)(x16 + (size_t)node * 128))[lane];

  // --- gather (rounds 0+1 of both sets prefetched: 16 uint4 in flight) ---
  {
    half2v mxA[4], mnA[4], mxB[4], mnB[4];
    float sA[8], sB[8];
    const half_t NINF = (half_t)(-INFINITY), PINF = (half_t)INFINITY;
#pragma unroll
    for (int p = 0; p < 4; ++p) {
      mxA[p] = (half2v){NINF, NINF}; mnA[p] = (half2v){PINF, PINF};
      mxB[p] = (half2v){NINF, NINF}; mnB[p] = (half2v){PINF, PINF};
    }
#pragma unroll
    for (int e = 0; e < 8; ++e) { sA[e] = 0.f; sB[e] = 0.f; }

    auto issue4 = [&](int entv, int c, int j, uint4* rv) {
#pragma unroll
      for (int u = 0; u < 4; ++u) {
        int r = j + u * 4 + slot;
        int rc = (r < c) ? r : (c - 1);
        int src = __shfl(entv, rc);
        rv[u] = *(const uint4*)(x16 + (size_t)src * 128 + d16 * 8);
      }
    };
    auto accum4 = [&](const uint4* rv, int j, int c, half2v* mx2, half2v* mn2,
                      float* sum) {
      half2v ps[4] = {(half2v){(half_t)0, (half_t)0}, (half2v){(half_t)0, (half_t)0},
                      (half2v){(half_t)0, (half_t)0}, (half2v){(half_t)0, (half_t)0}};
#pragma unroll
      for (int u = 0; u < 4; ++u) {
        int r = j + u * 4 + slot;
        if (r < c) {  // slot-uniform mask (16-lane groups)
          union { uint4 q; half2v p2[4]; } cc;
          cc.q = rv[u];
#pragma unroll
          for (int p = 0; p < 4; ++p) {
            mx2[p] = __builtin_elementwise_max(mx2[p], cc.p2[p]);
            mn2[p] = __builtin_elementwise_min(mn2[p], cc.p2[p]);
            ps[p] = ps[p] + cc.p2[p];  // v_pk_add_f16 partial (<=4 values)
          }
        }
      }
#pragma unroll
      for (int p = 0; p < 4; ++p) {  // fp32 flush once per 16-edge round
        sum[2 * p] += (float)ps[p][0];
        sum[2 * p + 1] += (float)ps[p][1];
      }
    };

    uint4 rva[4], rvb[4], rva2[4], rvb2[4];
    const bool p0 = c0 > 16, p1 = c1 > 16;
    if (c0 > 0) issue4(ent0, c0, 0, rva);
    if (c1 > 0) issue4(ent1, c1, 0, rvb);
    if (p0) issue4(ent0, c0, 16, rva2);      // round-1 prefetch (P(c>16)=0.43)
    if (p1) issue4(ent1, c1, 16, rvb2);      // 16 loads in flight
    if (c0 > 0) accum4(rva, 0, c0, mxA, mnA, sA);
    if (c1 > 0) accum4(rvb, 0, c1, mxB, mnB, sB);
    if (p0) accum4(rva2, 16, c0, mxA, mnA, sA);
    if (p1) accum4(rvb2, 16, c1, mxB, mnB, sB);
    for (int j = 32; j < c0; j += 16) { issue4(ent0, c0, j, rva); accum4(rva, j, c0, mxA, mnA, sA); }
    for (int j = 32; j < c1; j += 16) { issue4(ent1, c1, j, rvb); accum4(rvb, j, c1, mxB, mnB, sB); }

    // cross-slot reduce + write (slots 16 lanes apart), per set
    union HB { half2v h; int i; };
    auto finish = [&](int c, half2v* mx2, half2v* mn2, float* sum, int set) {
#pragma unroll
      for (int p = 0; p < 4; ++p) {
        HB a, b;
        a.h = mx2[p];
        b.i = __shfl_xor(a.i, 16); a.h = __builtin_elementwise_max(a.h, b.h);
        b.i = __shfl_xor(a.i, 32); a.h = __builtin_elementwise_max(a.h, b.h);
        mx2[p] = a.h;
        a.h = mn2[p];
        b.i = __shfl_xor(a.i, 16); a.h = __builtin_elementwise_min(a.h, b.h);
        b.i = __shfl_xor(a.i, 32); a.h = __builtin_elementwise_min(a.h, b.h);
        mn2[p] = a.h;
      }
#pragma unroll
      for (int e = 0; e < 8; ++e) {
        sum[e] += __shfl_xor(sum[e], 16);
        sum[e] += __shfl_xor(sum[e], 32);
      }
      float inv = 1.f / (float)(c > 1 ? c : 1);
      union { uint4 q; half2v p2[4]; half_t h[8]; } o;
      if (slot == 0) {
#pragma unroll
        for (int p = 0; p < 4; ++p) o.p2[p] = mx2[p];
      } else if (slot == 1) {
#pragma unroll
        for (int p = 0; p < 4; ++p) o.p2[p] = mn2[p];
      } else if (slot == 2) {
#pragma unroll
        for (int e = 0; e < 8; ++e) o.h[e] = (half_t)sum[e];
      } else {
#pragma unroll
        for (int e = 0; e < 8; ++e) o.h[e] = (half_t)(sum[e] * inv);
      }
      if (c == 0) o.q = make_uint4(0, 0, 0, 0);
      *(uint4*)(tokS + (size_t)(8 + wv * 8 + 4 * set + slot) * TS + d16 * 8) = o.q;
    };
    finish(c0, mxA, mnA, sA, 0);
    finish(c1, mxB, mnB, sB, 1);

    // self token -> row wv
    ((uint*)(tokS + wv * TS))[lane] = selfw;
  }
  __syncthreads();

  // GEMM1 (q only): wave wv covers q cols [wv*16, wv*16+16); B rows 0-15
  // (l15<8 real nodes; outputs for l15>=8 discarded).
  {
    int nt = wv;
    half8 aw[4];
#pragma unroll
    for (int ks = 0; ks < 4; ++ks)
      aw[ks] = *(const half8*)(w_swz + ((size_t)(nt * 4 + ks) * 64 + lane) * 8);
    int col0 = nt * 16 + quad * 4;
    float4 bias = *(const float4*)(b_in + col0);
    floatx4 acc = {0.f, 0.f, 0.f, 0.f};
#pragma unroll
    for (int ks = 0; ks < 4; ++ks) {
      half8 tb = *(const half8*)(tokS + l15 * TS + ks * 32 + quad * 8);
      acc = __builtin_amdgcn_mfma_f32_16x16x32_f16(aw[ks], tb, acc, 0, 0, 0);
    }
    if (l15 < 8) {
      half4 hv = {(half_t)(acc[0] + bias.x), (half_t)(acc[1] + bias.y),
                  (half_t)(acc[2] + bias.z), (half_t)(acc[3] + bias.w)};
      *(half4*)(qS + l15 * TS + col0) = hv;
    }
  }
  __syncthreads();

  // Y GEMM: Y[n,h,m] = sum_{j<32} q[n,h*32+j] * Wk[h*32+j, m].
  // Wave wv covers m-tile wv; 4 MFMAs (one per head), K=32.
  {
    int col0 = wv * 16 + quad * 4;
    int qr = l15 & 7;  // clamp B-row (l15>=8 outputs discarded)
#pragma unroll
    for (int h = 0; h < 4; ++h) {
      half8 awk = *(const half8*)(wkT_swz + ((size_t)(wv * 4 + h) * 64 + lane) * 8);
      half8 qb = *(const half8*)(qS + qr * TS + h * 32 + quad * 8);
      floatx4 acc = {0.f, 0.f, 0.f, 0.f};
      acc = __builtin_amdgcn_mfma_f32_16x16x32_f16(awk, qb, acc, 0, 0, 0);
      if (l15 < 8) {
        half4 hv = {(half_t)acc[0], (half_t)acc[1], (half_t)acc[2], (half_t)acc[3]};
        *(half4*)(yzS + (l15 * 4 + h) * TS + col0) = hv;
      }
    }
  }
  __syncthreads();

  // scores via MFMA (idle pipe): per wave, C[h,t] = Y(4x128) . tok^T(128x9).
  // A-frag row = l15&3 (Y head rows of own node), B-frag col = t = l15.
  // C layout: col = lane&15 = t, row = quad*4 + reg = h -> quad-0 lanes write.
  {
    int t = l15;
    int trow = (t == 0) ? wv : ((t <= 8) ? (8 + wv * 8 + (t - 1)) : wv);
    int yrow = wv * 4 + (l15 & 3);
    floatx4 acc = {0.f, 0.f, 0.f, 0.f};
#pragma unroll
    for (int ks = 0; ks < 4; ++ks) {
      half8 av = *(const half8*)(yzS + yrow * TS + ks * 32 + quad * 8);
      half8 bv = *(const half8*)(tokS + trow * TS + ks * 32 + quad * 8);
      acc = __builtin_amdgcn_mfma_f32_16x16x32_f16(av, bv, acc, 0, 0, 0);
    }
    if (quad == 0 && t < 9) {
      bool masked = (t >= 1) && (cntS[wv][(t - 1) >> 2] == 0);
#pragma unroll
      for (int h = 0; h < 4; ++h)
        scS[wv][h][t] = masked ? -1e30f : acc[h] * 0.17677669529663687f;
    }
  }

  if (lane < 4) {  // softmax per (node=wv, head=lane); same-wave LDS dataflow
    int h = lane;
    float m = -INFINITY;
#pragma unroll
    for (int t = 0; t < 9; ++t) m = fmaxf(m, scS[wv][h][t]);
    float ev[9], sum = 0.f;
#pragma unroll
    for (int t = 0; t < 9; ++t) { ev[t] = __expf(scS[wv][h][t] - m); sum += ev[t]; }
    float inv = 1.f / sum;
#pragma unroll
    for (int t = 0; t < 9; ++t) scS[wv][h][t] = ev[t] * inv;
  }

  // Z-phase: Z[n,h,k] = sum_t attn[h,t]*tok[t,k] -> yzS rows wv*4+h (Y dead;
  // wave-private rows). Lane covers dims 2*lane, 2*lane+1.
  {
    float za[4] = {0.f, 0.f, 0.f, 0.f}, zb[4] = {0.f, 0.f, 0.f, 0.f};
#pragma unroll
    for (int t = 0; t < 9; ++t) {
      int trow = (t == 0) ? wv : (8 + wv * 8 + (t - 1));
      half2v tv = *(const half2v*)(tokS + trow * TS + 2 * lane);
      float t0 = (float)tv[0], t1 = (float)tv[1];
#pragma unroll
      for (int h = 0; h < 4; ++h) {
        float a = scS[wv][h][t];
        za[h] = fmaf(a, t0, za[h]);
        zb[h] = fmaf(a, t1, zb[h]);
      }
    }
#pragma unroll
    for (int h = 0; h < 4; ++h) {
      half2v zv = {(half_t)za[h], (half_t)zb[h]};
      *(half2v*)(yzS + (wv * 4 + h) * TS + 2 * lane) = zv;
    }
  }
  __syncthreads();

  // GEMM2: out[node][n] = sum_{ksc} W2[n][ksc] * Z[node][h(ksc)] + b2. K=512.
  // Weight loads batched 8-deep (one vmcnt group per 8 MFMAs).
  float* oo = (float*)tokS;  // fp32, node rows; tokens dead after Z
  {
    floatx4 acc = {0.f, 0.f, 0.f, 0.f};
#pragma unroll
    for (int hp = 0; hp < 2; ++hp) {
      half8 awb[8];
#pragma unroll
      for (int i = 0; i < 8; ++i)
        awb[i] = *(const half8*)(wo_swz + ((size_t)(wv * 16 + hp * 8 + i) * 64 + lane) * 8);
#pragma unroll
      for (int i = 0; i < 8; ++i) {
        int ksc = hp * 8 + i;
        int h = ksc >> 2;
        int zr = (l15 < 8) ? (l15 * 4 + h) : h;
        half8 ob = *(const half8*)(yzS + zr * TS + (ksc & 3) * 32 + quad * 8);
        acc = __builtin_amdgcn_mfma_f32_16x16x32_f16(awb[i], ob, acc, 0, 0, 0);
      }
    }
    if (l15 < 8) {
      int col0 = wv * 16 + quad * 4;
      float4 bias = *(const float4*)(b2 + col0);
      float4 r;
      r.x = acc[0] + bias.x; r.y = acc[1] + bias.y;
      r.z = acc[2] + bias.z; r.w = acc[3] + bias.w;
      *(float4*)(oo + l15 * OS + col0) = r;
    }
  }
  __syncthreads();

  // LayerNorm per node (wave wv = node; lane covers 2 cols)
  {
    float v[2];
    float sum = 0.f, sq = 0.f;
#pragma unroll
    for (int u = 0; u < 2; ++u) {
      int c = lane + 64 * u;
      v[u] = oo[wv * OS + c];
      sum += v[u];
      sq += v[u] * v[u];
    }
#pragma unroll
    for (int m = 1; m < 64; m <<= 1) {
      sum += __shfl_xor(sum, m);
      sq += __shfl_xor(sq, m);
    }
    float mu = sum * (1.f / 128.f);
    float var = sq * (1.f / 128.f) - mu * mu;
    float rs = rsqrtf(var + 1e-5f);
#pragma unroll
    for (int u = 0; u < 2; ++u) {
      int c = lane + 64 * u;
      out[(size_t)node * 128 + c] = (v[u] - mu) * rs * gamma[c] + beta[c];
    }
  }
}

// ---------------- launch ----------------

extern "C" void kernel_launch(void* const* d_in, const int* in_sizes, int n_in,
                              void* d_out, int out_size, void* d_ws, size_t ws_size,
                              hipStream_t stream) {
  const float* x = (const float*)d_in[0];
  const int* ei0 = (const int*)d_in[1];
  const int* ei1 = (const int*)d_in[2];
  const float* w_in = (const float*)d_in[3];
  const float* b_in = (const float*)d_in[4];
  const float* w_out = (const float*)d_in[5];
  const float* b_out = (const float*)d_in[6];
  const float* gamma = (const float*)d_in[7];
  const float* beta = (const float*)d_in[8];
  float* out = (float*)d_out;

  char* wsB = (char*)d_ws;
  size_t off = 0;
  int* cursor = (int*)(wsB + off);       off += ((size_t)2 * NBINS * 4 + 15) & ~(size_t)15;
  unsigned int* arena = (unsigned int*)(wsB + off);
  off += (size_t)2 * NBINS * BSTRIDE * 4;
  int* cnt0 = (int*)(wsB + off); off += (size_t)NNODES * 4;
  int* cnt1 = (int*)(wsB + off); off += (size_t)NNODES * 4;
  ushort_t* A0 = (ushort_t*)(wsB + off); off += (size_t)NNODES * CAP * 2;
  ushort_t* A1 = (ushort_t*)(wsB + off); off += (size_t)NNODES * CAP * 2;
  off = (off + 15) & ~(size_t)15;
  half_t* w_swz = (half_t*)(wsB + off);   off += (size_t)WSWZ_SLOTS * 8 * 2;
  half_t* wkT_swz = (half_t*)(wsB + off); off += (size_t)2048 * 8 * 2;
  half_t* wo_swz = (half_t*)(wsB + off);  off += (size_t)8192 * 8 * 2;
  float* b2 = (float*)(wsB + off);        off += 128 * sizeof(float);
  half_t* x16 = (half_t*)(wsB + off);     off += (size_t)NNODES * 128 * 2;

  hipMemsetAsync(cursor, 0, 2 * NBINS * sizeof(int), stream);

  prep1_kernel<<<2 * P1PS + PREP_BLOCKS, 256, 0, stream>>>(
      ei0, ei1, cursor, arena, w_in, w_out, b_in, b_out, x,
      w_swz, wkT_swz, wo_swz, b2, x16);
  prep2_kernel<<<2 * NBINS, 256, 0, stream>>>(cursor, arena, cnt0, cnt1, A0, A1);
  fused_attn_kernel<<<NNODES / NPB, 512, 0, stream>>>(x16, cnt0, A0, cnt1, A1,
                                                      w_swz, wkT_swz, wo_swz,
                                                      b_in, b2, gamma, beta, out);
}

// Round 10
// 237.456 us; speedup vs baseline: 1.1350x; 1.1350x over previous
//
#include <hip/hip_runtime.h>
#include <hip/hip_fp16.h>
#include <math.h>

#define NNODES 50000
#define NEDGES 800000
#define D 128
#define NPB 8            // nodes per fused block (8 waves, 512 threads)
#define TROWS 72         // token rows: 0-7 self, 8-71 aggregates
#define TS 136           // LDS row stride (halfs): 272 B
#define OS 132           // oo row stride (floats)
#define CAP 64           // bucket capacity per (node,set): Poisson(16), P(>64) ~ 1e-20
#define NBINS 196        // coarse bins of 256 nodes (dst >> 8)
#define BSTRIDE 4608     // arena records per bin: Poisson(4096) + 8 sigma
#define EPB1 4096        // edges per phase-1 block
#define P1PS ((NEDGES + EPB1 - 1) / EPB1)   // 196 phase-1 blocks per set
// kernel-A streaming slot map (after the 392 phase-1 scatter blocks):
//   [0, 2048)        w_swz   : q weight tiles (w_in rows 0-127)
//   [2048, 4096)     wkT_swz : Wk^T per-head A-frags for the Y GEMM
//   [4096, 12288)    wo_swz  : W2_h per-head fused output weights
//   [12288, 12416)   b2      : w_out @ vb + b_out
//   [12416, ...)     x16     : x -> fp16
#define WSWZ_SLOTS 2048
#define WKT_BASE 2048
#define WO_BASE 4096
#define B2_BASE 12288
#define X16_BASE 12416
#define PREP_SLOTS (X16_BASE + NNODES * D / 4)
#define PREP_BLOCKS ((PREP_SLOTS + 255) / 256)

typedef _Float16 half_t;
typedef half_t half2v __attribute__((ext_vector_type(2)));
typedef half_t half4 __attribute__((ext_vector_type(4)));
typedef half_t half8 __attribute__((ext_vector_type(8)));
typedef float floatx4 __attribute__((ext_vector_type(4)));
typedef unsigned short ushort_t;

// Round-10: fused reverted to the round-8 body (140us proven; round-9's
// 16-deep prefetch + (512,4) cut occupancy 62->42 and cost +26us) with ONE
// change: __launch_bounds__(512,8). Evidence across rounds 0-9: measured
// occupancy tracks the launch-bounds waves/EU hint ((512,5)->62.8% vs the
// 62.5% the hint implies; (512,4)->42-50%). (512,8) requests 32 waves/CU;
// VGPR cap 64 vs the kernel's measured need of 40 -> no squeeze expected.
// Falsifiers: WRITE_SIZE >> 25MB (spill -> revert to (512,5)); occupancy
// unchanged (hint doesn't gate residency -> abandon this lever).
// Prep kept in round-9 form (binning + streaming overlapped in kernel A,
// pure phase-2 in kernel B; gap 103us vs round-8's 109us).
// Algebra (rounds 3/6, verified): scores via y_h = Wk_h^T q_h; output via
// W2_h = w_out_h @ vw, Z[h,:] = attn[h,:] @ tok, b2 = w_out @ vb + b_out.

// ---- kernel A: phase-1 binning (392 blocks) + streaming ----

__global__ __launch_bounds__(256) void prep1_kernel(
    const int* __restrict__ ei0, const int* __restrict__ ei1,
    int* __restrict__ cursor, unsigned int* __restrict__ arena,
    const float* __restrict__ w_in, const float* __restrict__ w_out,
    const float* __restrict__ b_in, const float* __restrict__ b_out,
    const float* __restrict__ x,
    half_t* __restrict__ w_swz, half_t* __restrict__ wkT_swz,
    half_t* __restrict__ wo_swz,
    float* __restrict__ b2, half_t* __restrict__ x16) {
  const int t = threadIdx.x;
  const int b = blockIdx.x;
  if (b < 2 * P1PS) {  // phase-1 binning
    __shared__ int hist[256], cur[256], baseA[256];
    const int set = (b >= P1PS);
    const int blk = set ? (b - P1PS) : b;
    const int* ei = set ? ei1 : ei0;
    hist[t] = 0; cur[t] = 0;
    __syncthreads();
    int dd[16], ss[16];
#pragma unroll
    for (int g = 0; g < 4; ++g) {
      int e = blk * EPB1 + g * 1024 + t * 4;
      if (e < NEDGES) {  // NEDGES % 4 == 0 -> int4 safe
        int4 dv = *(const int4*)(ei + NEDGES + e);
        int4 sv = *(const int4*)(ei + e);
        dd[g * 4 + 0] = dv.x; dd[g * 4 + 1] = dv.y;
        dd[g * 4 + 2] = dv.z; dd[g * 4 + 3] = dv.w;
        ss[g * 4 + 0] = sv.x; ss[g * 4 + 1] = sv.y;
        ss[g * 4 + 2] = sv.z; ss[g * 4 + 3] = sv.w;
      } else {
        dd[g * 4 + 0] = -1; dd[g * 4 + 1] = -1; dd[g * 4 + 2] = -1; dd[g * 4 + 3] = -1;
        ss[g * 4 + 0] = 0;  ss[g * 4 + 1] = 0;  ss[g * 4 + 2] = 0;  ss[g * 4 + 3] = 0;
      }
    }
#pragma unroll
    for (int i = 0; i < 16; ++i)
      if (dd[i] >= 0) atomicAdd(&hist[dd[i] >> 8], 1);
    __syncthreads();
    if (t < NBINS) {  // per-(block,bin) arena reservation: the ONLY device atomics
      int h = hist[t];
      baseA[t] = h ? atomicAdd(&cursor[set * NBINS + t], h) : 0;
    }
    __syncthreads();
#pragma unroll
    for (int i = 0; i < 16; ++i) {
      if (dd[i] >= 0) {
        int bin = dd[i] >> 8;
        int pos = atomicAdd(&cur[bin], 1) + baseA[bin];
        if (pos < BSTRIDE)
          arena[(size_t)(set * NBINS + bin) * BSTRIDE + pos] =
              ((unsigned)(dd[i] & 255) << 16) | (unsigned)ss[i];
      }
    }
    return;
  }
  int slot = (b - 2 * P1PS) * 256 + t;
  if (slot < WSWZ_SLOTS) {  // q weight tiles (w_in rows 0-127)
    int c = slot >> 6, l = slot & 63;
    int nt = c >> 2, ks = c & 3;
    int n = nt * 16 + (l & 15);
    int kb = ks * 32 + (l >> 4) * 8;
    half_t* dst = w_swz + (size_t)slot * 8;
#pragma unroll
    for (int j = 0; j < 8; ++j) dst[j] = (half_t)w_in[n * 128 + kb + j];
  } else if (slot < WO_BASE) {  // Wk^T per-head A-frags: chunk c2 = mt*4 + h
    int s2 = slot - WKT_BASE;       // 0..2047
    int c2 = s2 >> 6, l = s2 & 63;  // chunk 0..31
    int mt = c2 >> 2, h = c2 & 3;
    int m = mt * 16 + (l & 15);
    int j0 = (l >> 4) * 8;
    half_t* dst = wkT_swz + (size_t)s2 * 8;
#pragma unroll
    for (int j = 0; j < 8; ++j)
      dst[j] = (half_t)w_in[(size_t)(128 + h * 32 + j0 + j) * 128 + m];
  } else if (slot < B2_BASE) {  // W2_h, swizzled; K-chunks c2 = nt*16 + ksc
    int s2 = slot - WO_BASE;
    int c2 = s2 >> 6, l = s2 & 63;
    int nt = c2 >> 4, ksc = c2 & 15;
    int n = nt * 16 + (l & 15);
    int h = ksc >> 2;
    int kb = (ksc & 3) * 32 + (l >> 4) * 8;
    float acc[8] = {0.f, 0.f, 0.f, 0.f, 0.f, 0.f, 0.f, 0.f};
    for (int jj = 0; jj < 32; ++jj) {  // jp = h*32 + jj
      float wo = w_out[n * 128 + h * 32 + jj];
      const float* wr = w_in + (size_t)(256 + h * 32 + jj) * 128 + kb;
#pragma unroll
      for (int j = 0; j < 8; ++j) acc[j] = fmaf(wo, wr[j], acc[j]);
    }
    half_t* dst = wo_swz + (size_t)s2 * 8;
#pragma unroll
    for (int j = 0; j < 8; ++j) dst[j] = (half_t)acc[j];
  } else if (slot < X16_BASE) {  // b2 = w_out @ vb + b_out
    int i = slot - B2_BASE;
    float acc = b_out[i];
    for (int j = 0; j < 128; ++j) acc = fmaf(w_out[i * 128 + j], b_in[256 + j], acc);
    b2[i] = acc;
  } else {
    int idx = slot - X16_BASE;
    if (idx < NNODES * D / 4) {
      float4 v = ((const float4*)x)[idx];
      union { half_t h[4]; uint2 u64; } p;
      p.h[0] = (half_t)v.x; p.h[1] = (half_t)v.y;
      p.h[2] = (half_t)v.z; p.h[3] = (half_t)v.w;
      ((uint2*)x16)[idx] = p.u64;
    }
  }
}

// ---- kernel B: phase-2 fine bucketing only (392 blocks) ----

__global__ __launch_bounds__(256) void prep2_kernel(
    const int* __restrict__ cursor, const unsigned int* __restrict__ arena,
    int* __restrict__ cnt0, int* __restrict__ cnt1,
    ushort_t* __restrict__ A0, ushort_t* __restrict__ A1) {
  __shared__ int cntL[256];
  const int t = threadIdx.x;
  const int b = blockIdx.x;
  int set = (b >= NBINS);
  int bin = set ? (b - NBINS) : b;
  cntL[t] = 0;
  __syncthreads();
  int T = cursor[set * NBINS + bin];
  T = T > BSTRIDE ? BSTRIDE : T;
  ushort_t* A = set ? A1 : A0;
  int* cnt = set ? cnt1 : cnt0;
  const unsigned* arn = arena + (size_t)(set * NBINS + bin) * BSTRIDE;
  for (int i = t; i < T; i += 256) {
    unsigned rec = arn[i];
    int r = (rec >> 16) & 0xFF;
    int pos = atomicAdd(&cntL[r], 1);  // LDS atomic — fine counting is free
    if (pos < CAP)
      A[(size_t)(bin * 256 + r) * CAP + pos] = (ushort_t)(rec & 0xFFFF);
  }
  __syncthreads();
  int idx = bin * 256 + t;
  if (idx < NNODES) cnt[idx] = cntL[t] > CAP ? CAP : cntL[t];
}

// ---- fused gather + q proj + Y GEMM + MFMA scores + softmax + Z + W2 GEMM + LN ----
// Round-8 body verbatim; only the launch-bounds hint raised to (512,8).

__global__ __launch_bounds__(512, 8) void fused_attn_kernel(
    const half_t* __restrict__ x16,
    const int* __restrict__ cnt0, const ushort_t* __restrict__ A0,
    const int* __restrict__ cnt1, const ushort_t* __restrict__ A1,
    const half_t* __restrict__ w_swz, const half_t* __restrict__ wkT_swz,
    const half_t* __restrict__ wo_swz,
    const float* __restrict__ b_in, const float* __restrict__ b2,
    const float* __restrict__ gamma, const float* __restrict__ beta,
    float* __restrict__ out) {
  __shared__ half_t tokS[TROWS * TS];  // 19584 B; oo fp32 aliases rows 0-15 post-Z
  __shared__ half_t qS[8 * TS];        // 2176 B: q of node r at row r
  __shared__ half_t yzS[32 * TS];      // 8704 B: Y rows n*4+h, overwritten by Z
  __shared__ float scS[NPB][4][9];     // 1152 B
  __shared__ int cntS[NPB][2];         // 64 B

  const int tid = threadIdx.x;
  const int lane = tid & 63, wv = tid >> 6;
  const int quad = lane >> 4, l15 = lane & 15;
  const int slot = quad;      // gather row slot 0..3
  const int d16 = l15;        // gather dim block (8 dims)
  const int node = blockIdx.x * NPB + wv;
  const int node_s = __builtin_amdgcn_readfirstlane(node);  // wave-uniform -> s_load

  // --- counts + bucket entries (contiguous 128 B/node; counts pre-clamped <=64) ---
  int c0 = cnt0[node_s];
  int c1 = cnt1[node_s];
  if (lane == 0) { cntS[wv][0] = c0; cntS[wv][1] = c1; }
  int ent0 = A0[(size_t)node_s * CAP + lane];  // lanes >= c0 read garbage, never selected
  int ent1 = A1[(size_t)node_s * CAP + lane];
  uint selfw = ((const uint*)(x16 + (size_t)node * 128))[lane];

  // --- gather (8 loads in flight; sums in f16 partials, fp32 flush per round) ---
  {
    half2v mxA[4], mnA[4], mxB[4], mnB[4];
    float sA[8], sB[8];
    const half_t NINF = (half_t)(-INFINITY), PINF = (half_t)INFINITY;
#pragma unroll
    for (int p = 0; p < 4; ++p) {
      mxA[p] = (half2v){NINF, NINF}; mnA[p] = (half2v){PINF, PINF};
      mxB[p] = (half2v){NINF, NINF}; mnB[p] = (half2v){PINF, PINF};
    }
#pragma unroll
    for (int e = 0; e < 8; ++e) { sA[e] = 0.f; sB[e] = 0.f; }

    auto issue4 = [&](int entv, int c, int j, uint4* rv) {
#pragma unroll
      for (int u = 0; u < 4; ++u) {
        int r = j + u * 4 + slot;
        int rc = (r < c) ? r : (c - 1);
        int src = __shfl(entv, rc);
        rv[u] = *(const uint4*)(x16 + (size_t)src * 128 + d16 * 8);
      }
    };
    auto accum4 = [&](const uint4* rv, int j, int c, half2v* mx2, half2v* mn2,
                      float* sum) {
      half2v ps[4] = {(half2v){(half_t)0, (half_t)0}, (half2v){(half_t)0, (half_t)0},
                      (half2v){(half_t)0, (half_t)0}, (half2v){(half_t)0, (half_t)0}};
#pragma unroll
      for (int u = 0; u < 4; ++u) {
        int r = j + u * 4 + slot;
        if (r < c) {  // slot-uniform mask (16-lane groups)
          union { uint4 q; half2v p2[4]; } cc;
          cc.q = rv[u];
#pragma unroll
          for (int p = 0; p < 4; ++p) {
            mx2[p] = __builtin_elementwise_max(mx2[p], cc.p2[p]);
            mn2[p] = __builtin_elementwise_min(mn2[p], cc.p2[p]);
            ps[p] = ps[p] + cc.p2[p];  // v_pk_add_f16 partial (<=4 values)
          }
        }
      }
#pragma unroll
      for (int p = 0; p < 4; ++p) {  // fp32 flush once per 16-edge round
        sum[2 * p] += (float)ps[p][0];
        sum[2 * p + 1] += (float)ps[p][1];
      }
    };

    uint4 rva[4], rvb[4];
    if (c0 > 0) issue4(ent0, c0, 0, rva);
    if (c1 > 0) issue4(ent1, c1, 0, rvb);   // 8 loads in flight
    if (c0 > 0) accum4(rva, 0, c0, mxA, mnA, sA);
    if (c1 > 0) accum4(rvb, 0, c1, mxB, mnB, sB);
    for (int j = 16; j < c0; j += 16) { issue4(ent0, c0, j, rva); accum4(rva, j, c0, mxA, mnA, sA); }
    for (int j = 16; j < c1; j += 16) { issue4(ent1, c1, j, rvb); accum4(rvb, j, c1, mxB, mnB, sB); }

    // cross-slot reduce + write (slots 16 lanes apart), per set
    union HB { half2v h; int i; };
    auto finish = [&](int c, half2v* mx2, half2v* mn2, float* sum, int set) {
#pragma unroll
      for (int p = 0; p < 4; ++p) {
        HB a, b;
        a.h = mx2[p];
        b.i = __shfl_xor(a.i, 16); a.h = __builtin_elementwise_max(a.h, b.h);
        b.i = __shfl_xor(a.i, 32); a.h = __builtin_elementwise_max(a.h, b.h);
        mx2[p] = a.h;
        a.h = mn2[p];
        b.i = __shfl_xor(a.i, 16); a.h = __builtin_elementwise_min(a.h, b.h);
        b.i = __shfl_xor(a.i, 32); a.h = __builtin_elementwise_min(a.h, b.h);
        mn2[p] = a.h;
      }
#pragma unroll
      for (int e = 0; e < 8; ++e) {
        sum[e] += __shfl_xor(sum[e], 16);
        sum[e] += __shfl_xor(sum[e], 32);
      }
      float inv = 1.f / (float)(c > 1 ? c : 1);
      union { uint4 q; half2v p2[4]; half_t h[8]; } o;
      if (slot == 0) {
#pragma unroll
        for (int p = 0; p < 4; ++p) o.p2[p] = mx2[p];
      } else if (slot == 1) {
#pragma unroll
        for (int p = 0; p < 4; ++p) o.p2[p] = mn2[p];
      } else if (slot == 2) {
#pragma unroll
        for (int e = 0; e < 8; ++e) o.h[e] = (half_t)sum[e];
      } else {
#pragma unroll
        for (int e = 0; e < 8; ++e) o.h[e] = (half_t)(sum[e] * inv);
      }
      if (c == 0) o.q = make_uint4(0, 0, 0, 0);
      *(uint4*)(tokS + (size_t)(8 + wv * 8 + 4 * set + slot) * TS + d16 * 8) = o.q;
    };
    finish(c0, mxA, mnA, sA, 0);
    finish(c1, mxB, mnB, sB, 1);

    // self token -> row wv
    ((uint*)(tokS + wv * TS))[lane] = selfw;
  }
  __syncthreads();

  // GEMM1 (q only): wave wv covers q cols [wv*16, wv*16+16); B rows 0-15
  // (l15<8 real nodes; outputs for l15>=8 discarded).
  {
    int nt = wv;
    half8 aw[4];
#pragma unroll
    for (int ks = 0; ks < 4; ++ks)
      aw[ks] = *(const half8*)(w_swz + ((size_t)(nt * 4 + ks) * 64 + lane) * 8);
    int col0 = nt * 16 + quad * 4;
    float4 bias = *(const float4*)(b_in + col0);
    floatx4 acc = {0.f, 0.f, 0.f, 0.f};
#pragma unroll
    for (int ks = 0; ks < 4; ++ks) {
      half8 tb = *(const half8*)(tokS + l15 * TS + ks * 32 + quad * 8);
      acc = __builtin_amdgcn_mfma_f32_16x16x32_f16(aw[ks], tb, acc, 0, 0, 0);
    }
    if (l15 < 8) {
      half4 hv = {(half_t)(acc[0] + bias.x), (half_t)(acc[1] + bias.y),
                  (half_t)(acc[2] + bias.z), (half_t)(acc[3] + bias.w)};
      *(half4*)(qS + l15 * TS + col0) = hv;
    }
  }
  __syncthreads();

  // Y GEMM: Y[n,h,m] = sum_{j<32} q[n,h*32+j] * Wk[h*32+j, m].
  // Wave wv covers m-tile wv; 4 MFMAs (one per head), K=32.
  {
    int col0 = wv * 16 + quad * 4;
    int qr = l15 & 7;  // clamp B-row (l15>=8 outputs discarded)
#pragma unroll
    for (int h = 0; h < 4; ++h) {
      half8 awk = *(const half8*)(wkT_swz + ((size_t)(wv * 4 + h) * 64 + lane) * 8);
      half8 qb = *(const half8*)(qS + qr * TS + h * 32 + quad * 8);
      floatx4 acc = {0.f, 0.f, 0.f, 0.f};
      acc = __builtin_amdgcn_mfma_f32_16x16x32_f16(awk, qb, acc, 0, 0, 0);
      if (l15 < 8) {
        half4 hv = {(half_t)acc[0], (half_t)acc[1], (half_t)acc[2], (half_t)acc[3]};
        *(half4*)(yzS + (l15 * 4 + h) * TS + col0) = hv;
      }
    }
  }
  __syncthreads();

  // scores via MFMA (idle pipe): per wave, C[h,t] = Y(4x128) . tok^T(128x9).
  // A-frag row = l15&3 (Y head rows of own node), B-frag col = t = l15.
  // C layout: col = lane&15 = t, row = quad*4 + reg = h -> quad-0 lanes write.
  {
    int t = l15;
    int trow = (t == 0) ? wv : ((t <= 8) ? (8 + wv * 8 + (t - 1)) : wv);
    int yrow = wv * 4 + (l15 & 3);
    floatx4 acc = {0.f, 0.f, 0.f, 0.f};
#pragma unroll
    for (int ks = 0; ks < 4; ++ks) {
      half8 av = *(const half8*)(yzS + yrow * TS + ks * 32 + quad * 8);
      half8 bv = *(const half8*)(tokS + trow * TS + ks * 32 + quad * 8);
      acc = __builtin_amdgcn_mfma_f32_16x16x32_f16(av, bv, acc, 0, 0, 0);
    }
    if (quad == 0 && t < 9) {
      bool masked = (t >= 1) && (cntS[wv][(t - 1) >> 2] == 0);
#pragma unroll
      for (int h = 0; h < 4; ++h)
        scS[wv][h][t] = masked ? -1e30f : acc[h] * 0.17677669529663687f;
    }
  }

  if (lane < 4) {  // softmax per (node=wv, head=lane); same-wave LDS dataflow
    int h = lane;
    float m = -INFINITY;
#pragma unroll
    for (int t = 0; t < 9; ++t) m = fmaxf(m, scS[wv][h][t]);
    float ev[9], sum = 0.f;
#pragma unroll
    for (int t = 0; t < 9; ++t) { ev[t] = __expf(scS[wv][h][t] - m); sum += ev[t]; }
    float inv = 1.f / sum;
#pragma unroll
    for (int t = 0; t < 9; ++t) scS[wv][h][t] = ev[t] * inv;
  }

  // Z-phase: Z[n,h,k] = sum_t attn[h,t]*tok[t,k] -> yzS rows wv*4+h (Y dead;
  // wave-private rows). Lane covers dims 2*lane, 2*lane+1.
  {
    float za[4] = {0.f, 0.f, 0.f, 0.f}, zb[4] = {0.f, 0.f, 0.f, 0.f};
#pragma unroll
    for (int t = 0; t < 9; ++t) {
      int trow = (t == 0) ? wv : (8 + wv * 8 + (t - 1));
      half2v tv = *(const half2v*)(tokS + trow * TS + 2 * lane);
      float t0 = (float)tv[0], t1 = (float)tv[1];
#pragma unroll
      for (int h = 0; h < 4; ++h) {
        float a = scS[wv][h][t];
        za[h] = fmaf(a, t0, za[h]);
        zb[h] = fmaf(a, t1, zb[h]);
      }
    }
#pragma unroll
    for (int h = 0; h < 4; ++h) {
      half2v zv = {(half_t)za[h], (half_t)zb[h]};
      *(half2v*)(yzS + (wv * 4 + h) * TS + 2 * lane) = zv;
    }
  }
  __syncthreads();

  // GEMM2: out[node][n] = sum_{ksc} W2[n][ksc] * Z[node][h(ksc)] + b2. K=512.
  // Weight loads batched 8-deep (one vmcnt group per 8 MFMAs).
  float* oo = (float*)tokS;  // fp32, node rows; tokens dead after Z
  {
    floatx4 acc = {0.f, 0.f, 0.f, 0.f};
#pragma unroll
    for (int hp = 0; hp < 2; ++hp) {
      half8 awb[8];
#pragma unroll
      for (int i = 0; i < 8; ++i)
        awb[i] = *(const half8*)(wo_swz + ((size_t)(wv * 16 + hp * 8 + i) * 64 + lane) * 8);
#pragma unroll
      for (int i = 0; i < 8; ++i) {
        int ksc = hp * 8 + i;
        int h = ksc >> 2;
        int zr = (l15 < 8) ? (l15 * 4 + h) : h;
        half8 ob = *(const half8*)(yzS + zr * TS + (ksc & 3) * 32 + quad * 8);
        acc = __builtin_amdgcn_mfma_f32_16x16x32_f16(awb[i], ob, acc, 0, 0, 0);
      }
    }
    if (l15 < 8) {
      int col0 = wv * 16 + quad * 4;
      float4 bias = *(const float4*)(b2 + col0);
      float4 r;
      r.x = acc[0] + bias.x; r.y = acc[1] + bias.y;
      r.z = acc[2] + bias.z; r.w = acc[3] + bias.w;
      *(float4*)(oo + l15 * OS + col0) = r;
    }
  }
  __syncthreads();

  // LayerNorm per node (wave wv = node; lane covers 2 cols)
  {
    float v[2];
    float sum = 0.f, sq = 0.f;
#pragma unroll
    for (int u = 0; u < 2; ++u) {
      int c = lane + 64 * u;
      v[u] = oo[wv * OS + c];
      sum += v[u];
      sq += v[u] * v[u];
    }
#pragma unroll
    for (int m = 1; m < 64; m <<= 1) {
      sum += __shfl_xor(sum, m);
      sq += __shfl_xor(sq, m);
    }
    float mu = sum * (1.f / 128.f);
    float var = sq * (1.f / 128.f) - mu * mu;
    float rs = rsqrtf(var + 1e-5f);
#pragma unroll
    for (int u = 0; u < 2; ++u) {
      int c = lane + 64 * u;
      out[(size_t)node * 128 + c] = (v[u] - mu) * rs * gamma[c] + beta[c];
    }
  }
}

// ---------------- launch ----------------

extern "C" void kernel_launch(void* const* d_in, const int* in_sizes, int n_in,
                              void* d_out, int out_size, void* d_ws, size_t ws_size,
                              hipStream_t stream) {
  const float* x = (const float*)d_in[0];
  const int* ei0 = (const int*)d_in[1];
  const int* ei1 = (const int*)d_in[2];
  const float* w_in = (const float*)d_in[3];
  const float* b_in = (const float*)d_in[4];
  const float* w_out = (const float*)d_in[5];
  const float* b_out = (const float*)d_in[6];
  const float* gamma = (const float*)d_in[7];
  const float* beta = (const float*)d_in[8];
  float* out = (float*)d_out;

  char* wsB = (char*)d_ws;
  size_t off = 0;
  int* cursor = (int*)(wsB + off);       off += ((size_t)2 * NBINS * 4 + 15) & ~(size_t)15;
  unsigned int* arena = (unsigned int*)(wsB + off);
  off += (size_t)2 * NBINS * BSTRIDE * 4;
  int* cnt0 = (int*)(wsB + off); off += (size_t)NNODES * 4;
  int* cnt1 = (int*)(wsB + off); off += (size_t)NNODES * 4;
  ushort_t* A0 = (ushort_t*)(wsB + off); off += (size_t)NNODES * CAP * 2;
  ushort_t* A1 = (ushort_t*)(wsB + off); off += (size_t)NNODES * CAP * 2;
  off = (off + 15) & ~(size_t)15;
  half_t* w_swz = (half_t*)(wsB + off);   off += (size_t)WSWZ_SLOTS * 8 * 2;
  half_t* wkT_swz = (half_t*)(wsB + off); off += (size_t)2048 * 8 * 2;
  half_t* wo_swz = (half_t*)(wsB + off);  off += (size_t)8192 * 8 * 2;
  float* b2 = (float*)(wsB + off);        off += 128 * sizeof(float);
  half_t* x16 = (half_t*)(wsB + off);     off += (size_t)NNODES * 128 * 2;

  hipMemsetAsync(cursor, 0, 2 * NBINS * sizeof(int), stream);

  prep1_kernel<<<2 * P1PS + PREP_BLOCKS, 256, 0, stream>>>(
      ei0, ei1, cursor, arena, w_in, w_out, b_in, b_out, x,
      w_swz, wkT_swz, wo_swz, b2, x16);
  prep2_kernel<<<2 * NBINS, 256, 0, stream>>>(cursor, arena, cnt0, cnt1, A0, A1);
  fused_attn_kernel<<<NNODES / NPB, 512, 0, stream>>>(x16, cnt0, A0, cnt1, A1,
                                                      w_swz, wkT_swz, wo_swz,
                                                      b_in, b2, gamma, beta, out);
}

// Round 11
// 232.769 us; speedup vs baseline: 1.1579x; 1.0201x over previous
//
#include <hip/hip_runtime.h>
#include <hip/hip_fp16.h>
#include <math.h>

#define NNODES 50000
#define NEDGES 800000
#define D 128
#define NPB 8            // nodes per fused block (8 waves, 512 threads)
#define TROWS 72         // token rows: 0-7 self, 8-71 aggregates
#define TS 136           // LDS row stride (halfs): 272 B
#define OS 132           // oo row stride (floats)
#define CAP 64           // bucket capacity per (node,set): Poisson(16), P(>64) ~ 1e-20
#define NBINS 196        // coarse bins of 256 nodes (dst >> 8)
#define BSTRIDE 4608     // arena records per bin: Poisson(4096) + 8 sigma
#define EPB1 4096        // edges per phase-1 block
#define P1PS ((NEDGES + EPB1 - 1) / EPB1)   // 196 phase-1 blocks per set
// kernel-A streaming slot map (after the 392 phase-1 scatter blocks):
//   [0, 2048)        w_swz   : q weight tiles (w_in rows 0-127)
//   [2048, 4096)     wkT_swz : Wk^T per-head A-frags for the Y GEMM
//   [4096, 12288)    wo_swz  : W2_h per-head fused output weights
//   [12288, 12416)   b2      : w_out @ vb + b_out
//   [12416, ...)     x16     : x -> fp16
#define WSWZ_SLOTS 2048
#define WKT_BASE 2048
#define WO_BASE 4096
#define B2_BASE 12288
#define X16_BASE 12416
#define PREP_SLOTS (X16_BASE + NNODES * D / 4)
#define PREP_BLOCKS ((PREP_SLOTS + 255) / 256)

typedef _Float16 half_t;
typedef half_t half2v __attribute__((ext_vector_type(2)));
typedef half_t half4 __attribute__((ext_vector_type(4)));
typedef half_t half8 __attribute__((ext_vector_type(8)));
typedef float floatx4 __attribute__((ext_vector_type(4)));
typedef unsigned short ushort_t;

// Round-11:
// (a) phase-1 arena writes made COALESCED via block-local counting sort in
//     LDS (histogram -> prefix scan -> LDS scatter -> contiguous write-out).
//     The old path issued 1.6M random 4B stores -> ~100MB of write-allocate
//     line traffic (the unexplained ~40us of the 106us prep gap).
//     Record packs bin(8)|fine(8)|src(16); arena keeps low 24 bits.
// (b) fused GEMM2 weight batch 8->4 (awb was 32 VGPRs; under (512,8)'s
//     64-VGPR cap it spilled: round-10 WRITE_SIZE 25->62.5MB). Occupancy
//     hint (512,8) kept — it gated residency (62.8%->80.6%, 140->131.6us).
// Algebra (rounds 3/6, verified): scores via y_h = Wk_h^T q_h; output via
// W2_h = w_out_h @ vw, Z[h,:] = attn[h,:] @ tok, b2 = w_out @ vb + b_out.

// ---- kernel A: phase-1 binning (392 blocks, LDS-sorted) + streaming ----

__global__ __launch_bounds__(256) void prep1_kernel(
    const int* __restrict__ ei0, const int* __restrict__ ei1,
    int* __restrict__ cursor, unsigned int* __restrict__ arena,
    const float* __restrict__ w_in, const float* __restrict__ w_out,
    const float* __restrict__ b_in, const float* __restrict__ b_out,
    const float* __restrict__ x,
    half_t* __restrict__ w_swz, half_t* __restrict__ wkT_swz,
    half_t* __restrict__ wo_swz,
    float* __restrict__ b2, half_t* __restrict__ x16) {
  const int t = threadIdx.x;
  const int b = blockIdx.x;
  if (b < 2 * P1PS) {  // phase-1 binning with block-local counting sort
    __shared__ int hist[256], scan[256], cur[256], baseA[256];
    __shared__ unsigned recS[EPB1];  // 16 KB sorted records
    const int set = (b >= P1PS);
    const int blk = set ? (b - P1PS) : b;
    const int* ei = set ? ei1 : ei0;
    hist[t] = 0;
    __syncthreads();
    int bins[16];
    unsigned recs[16];
#pragma unroll
    for (int g = 0; g < 4; ++g) {
      int e = blk * EPB1 + g * 1024 + t * 4;
      if (e < NEDGES) {  // NEDGES % 4 == 0 -> int4 safe
        int4 dv = *(const int4*)(ei + NEDGES + e);
        int4 sv = *(const int4*)(ei + e);
        int dd[4] = {dv.x, dv.y, dv.z, dv.w};
        int ss[4] = {sv.x, sv.y, sv.z, sv.w};
#pragma unroll
        for (int u = 0; u < 4; ++u) {
          bins[g * 4 + u] = dd[u] >> 8;
          recs[g * 4 + u] = ((unsigned)(dd[u] & 255) << 16) | (unsigned)ss[u];
        }
      } else {
#pragma unroll
        for (int u = 0; u < 4; ++u) { bins[g * 4 + u] = -1; recs[g * 4 + u] = 0; }
      }
    }
#pragma unroll
    for (int i = 0; i < 16; ++i)
      if (bins[i] >= 0) atomicAdd(&hist[bins[i]], 1);
    __syncthreads();
    // inclusive Hillis-Steele scan of hist -> scan
    int v = hist[t];
    scan[t] = v;
    __syncthreads();
    for (int off = 1; off < 256; off <<= 1) {
      int y = (t >= off) ? scan[t - off] : 0;
      __syncthreads();
      scan[t] += y;
      __syncthreads();
    }
    // per-(block,bin) arena reservation: the ONLY device atomics (<=196/block)
    if (t < NBINS && v > 0) baseA[t] = atomicAdd(&cursor[set * NBINS + t], v);
    else baseA[t] = 0;
    cur[t] = scan[t] - v;  // exclusive prefix = LDS scatter cursor
    __syncthreads();
#pragma unroll
    for (int i = 0; i < 16; ++i) {
      if (bins[i] >= 0) {
        int p = atomicAdd(&cur[bins[i]], 1);
        recS[p] = ((unsigned)bins[i] << 24) | recs[i];
      }
    }
    __syncthreads();
    int tot = scan[255];
    for (int i = t; i < tot; i += 256) {  // consecutive i -> same-bin runs: coalesced
      unsigned r = recS[i];
      int bn = r >> 24;
      int ofs = baseA[bn] + (i - (scan[bn] - hist[bn]));
      if (ofs < BSTRIDE)
        arena[(size_t)(set * NBINS + bn) * BSTRIDE + ofs] = r & 0xFFFFFF;
    }
    return;
  }
  int slot = (b - 2 * P1PS) * 256 + t;
  if (slot < WSWZ_SLOTS) {  // q weight tiles (w_in rows 0-127)
    int c = slot >> 6, l = slot & 63;
    int nt = c >> 2, ks = c & 3;
    int n = nt * 16 + (l & 15);
    int kb = ks * 32 + (l >> 4) * 8;
    half_t* dst = w_swz + (size_t)slot * 8;
#pragma unroll
    for (int j = 0; j < 8; ++j) dst[j] = (half_t)w_in[n * 128 + kb + j];
  } else if (slot < WO_BASE) {  // Wk^T per-head A-frags: chunk c2 = mt*4 + h
    int s2 = slot - WKT_BASE;       // 0..2047
    int c2 = s2 >> 6, l = s2 & 63;  // chunk 0..31
    int mt = c2 >> 2, h = c2 & 3;
    int m = mt * 16 + (l & 15);
    int j0 = (l >> 4) * 8;
    half_t* dst = wkT_swz + (size_t)s2 * 8;
#pragma unroll
    for (int j = 0; j < 8; ++j)
      dst[j] = (half_t)w_in[(size_t)(128 + h * 32 + j0 + j) * 128 + m];
  } else if (slot < B2_BASE) {  // W2_h, swizzled; K-chunks c2 = nt*16 + ksc
    int s2 = slot - WO_BASE;
    int c2 = s2 >> 6, l = s2 & 63;
    int nt = c2 >> 4, ksc = c2 & 15;
    int n = nt * 16 + (l & 15);
    int h = ksc >> 2;
    int kb = (ksc & 3) * 32 + (l >> 4) * 8;
    float acc[8] = {0.f, 0.f, 0.f, 0.f, 0.f, 0.f, 0.f, 0.f};
    for (int jj = 0; jj < 32; ++jj) {  // jp = h*32 + jj
      float wo = w_out[n * 128 + h * 32 + jj];
      const float* wr = w_in + (size_t)(256 + h * 32 + jj) * 128 + kb;
#pragma unroll
      for (int j = 0; j < 8; ++j) acc[j] = fmaf(wo, wr[j], acc[j]);
    }
    half_t* dst = wo_swz + (size_t)s2 * 8;
#pragma unroll
    for (int j = 0; j < 8; ++j) dst[j] = (half_t)acc[j];
  } else if (slot < X16_BASE) {  // b2 = w_out @ vb + b_out
    int i = slot - B2_BASE;
    float acc = b_out[i];
    for (int j = 0; j < 128; ++j) acc = fmaf(w_out[i * 128 + j], b_in[256 + j], acc);
    b2[i] = acc;
  } else {
    int idx = slot - X16_BASE;
    if (idx < NNODES * D / 4) {
      float4 v = ((const float4*)x)[idx];
      union { half_t h[4]; uint2 u64; } p;
      p.h[0] = (half_t)v.x; p.h[1] = (half_t)v.y;
      p.h[2] = (half_t)v.z; p.h[3] = (half_t)v.w;
      ((uint2*)x16)[idx] = p.u64;
    }
  }
}

// ---- kernel B: phase-2 fine bucketing only (392 blocks) ----

__global__ __launch_bounds__(256) void prep2_kernel(
    const int* __restrict__ cursor, const unsigned int* __restrict__ arena,
    int* __restrict__ cnt0, int* __restrict__ cnt1,
    ushort_t* __restrict__ A0, ushort_t* __restrict__ A1) {
  __shared__ int cntL[256];
  const int t = threadIdx.x;
  const int b = blockIdx.x;
  int set = (b >= NBINS);
  int bin = set ? (b - NBINS) : b;
  cntL[t] = 0;
  __syncthreads();
  int T = cursor[set * NBINS + bin];
  T = T > BSTRIDE ? BSTRIDE : T;
  ushort_t* A = set ? A1 : A0;
  int* cnt = set ? cnt1 : cnt0;
  const unsigned* arn = arena + (size_t)(set * NBINS + bin) * BSTRIDE;
  for (int i = t; i < T; i += 256) {
    unsigned rec = arn[i];
    int r = (rec >> 16) & 0xFF;
    int pos = atomicAdd(&cntL[r], 1);  // LDS atomic — fine counting is free
    if (pos < CAP)
      A[(size_t)(bin * 256 + r) * CAP + pos] = (ushort_t)(rec & 0xFFFF);
  }
  __syncthreads();
  int idx = bin * 256 + t;
  if (idx < NNODES) cnt[idx] = cntL[t] > CAP ? CAP : cntL[t];
}

// ---- fused gather + q proj + Y GEMM + MFMA scores + softmax + Z + W2 GEMM + LN ----
// Round-10 body with GEMM2 weight batch 8->4 (spill relief under (512,8)).

__global__ __launch_bounds__(512, 8) void fused_attn_kernel(
    const half_t* __restrict__ x16,
    const int* __restrict__ cnt0, const ushort_t* __restrict__ A0,
    const int* __restrict__ cnt1, const ushort_t* __restrict__ A1,
    const half_t* __restrict__ w_swz, const half_t* __restrict__ wkT_swz,
    const half_t* __restrict__ wo_swz,
    const float* __restrict__ b_in, const float* __restrict__ b2,
    const float* __restrict__ gamma, const float* __restrict__ beta,
    float* __restrict__ out) {
  __shared__ half_t tokS[TROWS * TS];  // 19584 B; oo fp32 aliases rows 0-15 post-Z
  __shared__ half_t qS[8 * TS];        // 2176 B: q of node r at row r
  __shared__ half_t yzS[32 * TS];      // 8704 B: Y rows n*4+h, overwritten by Z
  __shared__ float scS[NPB][4][9];     // 1152 B
  __shared__ int cntS[NPB][2];         // 64 B

  const int tid = threadIdx.x;
  const int lane = tid & 63, wv = tid >> 6;
  const int quad = lane >> 4, l15 = lane & 15;
  const int slot = quad;      // gather row slot 0..3
  const int d16 = l15;        // gather dim block (8 dims)
  const int node = blockIdx.x * NPB + wv;
  const int node_s = __builtin_amdgcn_readfirstlane(node);  // wave-uniform -> s_load

  // --- counts + bucket entries (contiguous 128 B/node; counts pre-clamped <=64) ---
  int c0 = cnt0[node_s];
  int c1 = cnt1[node_s];
  if (lane == 0) { cntS[wv][0] = c0; cntS[wv][1] = c1; }
  int ent0 = A0[(size_t)node_s * CAP + lane];  // lanes >= c0 read garbage, never selected
  int ent1 = A1[(size_t)node_s * CAP + lane];
  uint selfw = ((const uint*)(x16 + (size_t)node * 128))[lane];

  // --- gather (8 loads in flight; sums in f16 partials, fp32 flush per round) ---
  {
    half2v mxA[4], mnA[4], mxB[4], mnB[4];
    float sA[8], sB[8];
    const half_t NINF = (half_t)(-INFINITY), PINF = (half_t)INFINITY;
#pragma unroll
    for (int p = 0; p < 4; ++p) {
      mxA[p] = (half2v){NINF, NINF}; mnA[p] = (half2v){PINF, PINF};
      mxB[p] = (half2v){NINF, NINF}; mnB[p] = (half2v){PINF, PINF};
    }
#pragma unroll
    for (int e = 0; e < 8; ++e) { sA[e] = 0.f; sB[e] = 0.f; }

    auto issue4 = [&](int entv, int c, int j, uint4* rv) {
#pragma unroll
      for (int u = 0; u < 4; ++u) {
        int r = j + u * 4 + slot;
        int rc = (r < c) ? r : (c - 1);
        int src = __shfl(entv, rc);
        rv[u] = *(const uint4*)(x16 + (size_t)src * 128 + d16 * 8);
      }
    };
    auto accum4 = [&](const uint4* rv, int j, int c, half2v* mx2, half2v* mn2,
                      float* sum) {
      half2v ps[4] = {(half2v){(half_t)0, (half_t)0}, (half2v){(half_t)0, (half_t)0},
                      (half2v){(half_t)0, (half_t)0}, (half2v){(half_t)0, (half_t)0}};
#pragma unroll
      for (int u = 0; u < 4; ++u) {
        int r = j + u * 4 + slot;
        if (r < c) {  // slot-uniform mask (16-lane groups)
          union { uint4 q; half2v p2[4]; } cc;
          cc.q = rv[u];
#pragma unroll
          for (int p = 0; p < 4; ++p) {
            mx2[p] = __builtin_elementwise_max(mx2[p], cc.p2[p]);
            mn2[p] = __builtin_elementwise_min(mn2[p], cc.p2[p]);
            ps[p] = ps[p] + cc.p2[p];  // v_pk_add_f16 partial (<=4 values)
          }
        }
      }
#pragma unroll
      for (int p = 0; p < 4; ++p) {  // fp32 flush once per 16-edge round
        sum[2 * p] += (float)ps[p][0];
        sum[2 * p + 1] += (float)ps[p][1];
      }
    };

    uint4 rva[4], rvb[4];
    if (c0 > 0) issue4(ent0, c0, 0, rva);
    if (c1 > 0) issue4(ent1, c1, 0, rvb);   // 8 loads in flight
    if (c0 > 0) accum4(rva, 0, c0, mxA, mnA, sA);
    if (c1 > 0) accum4(rvb, 0, c1, mxB, mnB, sB);
    for (int j = 16; j < c0; j += 16) { issue4(ent0, c0, j, rva); accum4(rva, j, c0, mxA, mnA, sA); }
    for (int j = 16; j < c1; j += 16) { issue4(ent1, c1, j, rvb); accum4(rvb, j, c1, mxB, mnB, sB); }

    // cross-slot reduce + write (slots 16 lanes apart), per set
    union HB { half2v h; int i; };
    auto finish = [&](int c, half2v* mx2, half2v* mn2, float* sum, int set) {
#pragma unroll
      for (int p = 0; p < 4; ++p) {
        HB a, b;
        a.h = mx2[p];
        b.i = __shfl_xor(a.i, 16); a.h = __builtin_elementwise_max(a.h, b.h);
        b.i = __shfl_xor(a.i, 32); a.h = __builtin_elementwise_max(a.h, b.h);
        mx2[p] = a.h;
        a.h = mn2[p];
        b.i = __shfl_xor(a.i, 16); a.h = __builtin_elementwise_min(a.h, b.h);
        b.i = __shfl_xor(a.i, 32); a.h = __builtin_elementwise_min(a.h, b.h);
        mn2[p] = a.h;
      }
#pragma unroll
      for (int e = 0; e < 8; ++e) {
        sum[e] += __shfl_xor(sum[e], 16);
        sum[e] += __shfl_xor(sum[e], 32);
      }
      float inv = 1.f / (float)(c > 1 ? c : 1);
      union { uint4 q; half2v p2[4]; half_t h[8]; } o;
      if (slot == 0) {
#pragma unroll
        for (int p = 0; p < 4; ++p) o.p2[p] = mx2[p];
      } else if (slot == 1) {
#pragma unroll
        for (int p = 0; p < 4; ++p) o.p2[p] = mn2[p];
      } else if (slot == 2) {
#pragma unroll
        for (int e = 0; e < 8; ++e) o.h[e] = (half_t)sum[e];
      } else {
#pragma unroll
        for (int e = 0; e < 8; ++e) o.h[e] = (half_t)(sum[e] * inv);
      }
      if (c == 0) o.q = make_uint4(0, 0, 0, 0);
      *(uint4*)(tokS + (size_t)(8 + wv * 8 + 4 * set + slot) * TS + d16 * 8) = o.q;
    };
    finish(c0, mxA, mnA, sA, 0);
    finish(c1, mxB, mnB, sB, 1);

    // self token -> row wv
    ((uint*)(tokS + wv * TS))[lane] = selfw;
  }
  __syncthreads();

  // GEMM1 (q only): wave wv covers q cols [wv*16, wv*16+16); B rows 0-15
  // (l15<8 real nodes; outputs for l15>=8 discarded).
  {
    int nt = wv;
    half8 aw[4];
#pragma unroll
    for (int ks = 0; ks < 4; ++ks)
      aw[ks] = *(const half8*)(w_swz + ((size_t)(nt * 4 + ks) * 64 + lane) * 8);
    int col0 = nt * 16 + quad * 4;
    float4 bias = *(const float4*)(b_in + col0);
    floatx4 acc = {0.f, 0.f, 0.f, 0.f};
#pragma unroll
    for (int ks = 0; ks < 4; ++ks) {
      half8 tb = *(const half8*)(tokS + l15 * TS + ks * 32 + quad * 8);
      acc = __builtin_amdgcn_mfma_f32_16x16x32_f16(aw[ks], tb, acc, 0, 0, 0);
    }
    if (l15 < 8) {
      half4 hv = {(half_t)(acc[0] + bias.x), (half_t)(acc[1] + bias.y),
                  (half_t)(acc[2] + bias.z), (half_t)(acc[3] + bias.w)};
      *(half4*)(qS + l15 * TS + col0) = hv;
    }
  }
  __syncthreads();

  // Y GEMM: Y[n,h,m] = sum_{j<32} q[n,h*32+j] * Wk[h*32+j, m].
  // Wave wv covers m-tile wv; 4 MFMAs (one per head), K=32.
  {
    int col0 = wv * 16 + quad * 4;
    int qr = l15 & 7;  // clamp B-row (l15>=8 outputs discarded)
#pragma unroll
    for (int h = 0; h < 4; ++h) {
      half8 awk = *(const half8*)(wkT_swz + ((size_t)(wv * 4 + h) * 64 + lane) * 8);
      half8 qb = *(const half8*)(qS + qr * TS + h * 32 + quad * 8);
      floatx4 acc = {0.f, 0.f, 0.f, 0.f};
      acc = __builtin_amdgcn_mfma_f32_16x16x32_f16(awk, qb, acc, 0, 0, 0);
      if (l15 < 8) {
        half4 hv = {(half_t)acc[0], (half_t)acc[1], (half_t)acc[2], (half_t)acc[3]};
        *(half4*)(yzS + (l15 * 4 + h) * TS + col0) = hv;
      }
    }
  }
  __syncthreads();

  // scores via MFMA (idle pipe): per wave, C[h,t] = Y(4x128) . tok^T(128x9).
  // A-frag row = l15&3 (Y head rows of own node), B-frag col = t = l15.
  // C layout: col = lane&15 = t, row = quad*4 + reg = h -> quad-0 lanes write.
  {
    int t = l15;
    int trow = (t == 0) ? wv : ((t <= 8) ? (8 + wv * 8 + (t - 1)) : wv);
    int yrow = wv * 4 + (l15 & 3);
    floatx4 acc = {0.f, 0.f, 0.f, 0.f};
#pragma unroll
    for (int ks = 0; ks < 4; ++ks) {
      half8 av = *(const half8*)(yzS + yrow * TS + ks * 32 + quad * 8);
      half8 bv = *(const half8*)(tokS + trow * TS + ks * 32 + quad * 8);
      acc = __builtin_amdgcn_mfma_f32_16x16x32_f16(av, bv, acc, 0, 0, 0);
    }
    if (quad == 0 && t < 9) {
      bool masked = (t >= 1) && (cntS[wv][(t - 1) >> 2] == 0);
#pragma unroll
      for (int h = 0; h < 4; ++h)
        scS[wv][h][t] = masked ? -1e30f : acc[h] * 0.17677669529663687f;
    }
  }

  if (lane < 4) {  // softmax per (node=wv, head=lane); same-wave LDS dataflow
    int h = lane;
    float m = -INFINITY;
#pragma unroll
    for (int t = 0; t < 9; ++t) m = fmaxf(m, scS[wv][h][t]);
    float ev[9], sum = 0.f;
#pragma unroll
    for (int t = 0; t < 9; ++t) { ev[t] = __expf(scS[wv][h][t] - m); sum += ev[t]; }
    float inv = 1.f / sum;
#pragma unroll
    for (int t = 0; t < 9; ++t) scS[wv][h][t] = ev[t] * inv;
  }

  // Z-phase: Z[n,h,k] = sum_t attn[h,t]*tok[t,k] -> yzS rows wv*4+h (Y dead;
  // wave-private rows). Lane covers dims 2*lane, 2*lane+1.
  {
    float za[4] = {0.f, 0.f, 0.f, 0.f}, zb[4] = {0.f, 0.f, 0.f, 0.f};
#pragma unroll
    for (int t = 0; t < 9; ++t) {
      int trow = (t == 0) ? wv : (8 + wv * 8 + (t - 1));
      half2v tv = *(const half2v*)(tokS + trow * TS + 2 * lane);
      float t0 = (float)tv[0], t1 = (float)tv[1];
#pragma unroll
      for (int h = 0; h < 4; ++h) {
        float a = scS[wv][h][t];
        za[h] = fmaf(a, t0, za[h]);
        zb[h] = fmaf(a, t1, zb[h]);
      }
    }
#pragma unroll
    for (int h = 0; h < 4; ++h) {
      half2v zv = {(half_t)za[h], (half_t)zb[h]};
      *(half2v*)(yzS + (wv * 4 + h) * TS + 2 * lane) = zv;
    }
  }
  __syncthreads();

  // GEMM2: out[node][n] = sum_{ksc} W2[n][ksc] * Z[node][h(ksc)] + b2. K=512.
  // Weight loads batched 4-deep (16 VGPRs vs round-10's 32: spill relief).
  float* oo = (float*)tokS;  // fp32, node rows; tokens dead after Z
  {
    floatx4 acc = {0.f, 0.f, 0.f, 0.f};
#pragma unroll
    for (int hp = 0; hp < 4; ++hp) {
      half8 awb[4];
#pragma unroll
      for (int i = 0; i < 4; ++i)
        awb[i] = *(const half8*)(wo_swz + ((size_t)(wv * 16 + hp * 4 + i) * 64 + lane) * 8);
#pragma unroll
      for (int i = 0; i < 4; ++i) {
        int ksc = hp * 4 + i;
        int h = ksc >> 2;  // == hp
        int zr = (l15 < 8) ? (l15 * 4 + h) : h;
        half8 ob = *(const half8*)(yzS + zr * TS + (ksc & 3) * 32 + quad * 8);
        acc = __builtin_amdgcn_mfma_f32_16x16x32_f16(awb[i], ob, acc, 0, 0, 0);
      }
    }
    if (l15 < 8) {
      int col0 = wv * 16 + quad * 4;
      float4 bias = *(const float4*)(b2 + col0);
      float4 r;
      r.x = acc[0] + bias.x; r.y = acc[1] + bias.y;
      r.z = acc[2] + bias.z; r.w = acc[3] + bias.w;
      *(float4*)(oo + l15 * OS + col0) = r;
    }
  }
  __syncthreads();

  // LayerNorm per node (wave wv = node; lane covers 2 cols)
  {
    float v[2];
    float sum = 0.f, sq = 0.f;
#pragma unroll
    for (int u = 0; u < 2; ++u) {
      int c = lane + 64 * u;
      v[u] = oo[wv * OS + c];
      sum += v[u];
      sq += v[u] * v[u];
    }
#pragma unroll
    for (int m = 1; m < 64; m <<= 1) {
      sum += __shfl_xor(sum, m);
      sq += __shfl_xor(sq, m);
    }
    float mu = sum * (1.f / 128.f);
    float var = sq * (1.f / 128.f) - mu * mu;
    float rs = rsqrtf(var + 1e-5f);
#pragma unroll
    for (int u = 0; u < 2; ++u) {
      int c = lane + 64 * u;
      out[(size_t)node * 128 + c] = (v[u] - mu) * rs * gamma[c] + beta[c];
    }
  }
}

// ---------------- launch ----------------

extern "C" void kernel_launch(void* const* d_in, const int* in_sizes, int n_in,
                              void* d_out, int out_size, void* d_ws, size_t ws_size,
                              hipStream_t stream) {
  const float* x = (const float*)d_in[0];
  const int* ei0 = (const int*)d_in[1];
  const int* ei1 = (const int*)d_in[2];
  const float* w_in = (const float*)d_in[3];
  const float* b_in = (const float*)d_in[4];
  const float* w_out = (const float*)d_in[5];
  const float* b_out = (const float*)d_in[6];
  const float* gamma = (const float*)d_in[7];
  const float* beta = (const float*)d_in[8];
  float* out = (float*)d_out;

  char* wsB = (char*)d_ws;
  size_t off = 0;
  int* cursor = (int*)(wsB + off);       off += ((size_t)2 * NBINS * 4 + 15) & ~(size_t)15;
  unsigned int* arena = (unsigned int*)(wsB + off);
  off += (size_t)2 * NBINS * BSTRIDE * 4;
  int* cnt0 = (int*)(wsB + off); off += (size_t)NNODES * 4;
  int* cnt1 = (int*)(wsB + off); off += (size_t)NNODES * 4;
  ushort_t* A0 = (ushort_t*)(wsB + off); off += (size_t)NNODES * CAP * 2;
  ushort_t* A1 = (ushort_t*)(wsB + off); off += (size_t)NNODES * CAP * 2;
  off = (off + 15) & ~(size_t)15;
  half_t* w_swz = (half_t*)(wsB + off);   off += (size_t)WSWZ_SLOTS * 8 * 2;
  half_t* wkT_swz = (half_t*)(wsB + off); off += (size_t)2048 * 8 * 2;
  half_t* wo_swz = (half_t*)(wsB + off);  off += (size_t)8192 * 8 * 2;
  float* b2 = (float*)(wsB + off);        off += 128 * sizeof(float);
  half_t* x16 = (half_t*)(wsB + off);     off += (size_t)NNODES * 128 * 2;

  hipMemsetAsync(cursor, 0, 2 * NBINS * sizeof(int), stream);

  prep1_kernel<<<2 * P1PS + PREP_BLOCKS, 256, 0, stream>>>(
      ei0, ei1, cursor, arena, w_in, w_out, b_in, b_out, x,
      w_swz, wkT_swz, wo_swz, b2, x16);
  prep2_kernel<<<2 * NBINS, 256, 0, stream>>>(cursor, arena, cnt0, cnt1, A0, A1);
  fused_attn_kernel<<<NNODES / NPB, 512, 0, stream>>>(x16, cnt0, A0, cnt1, A1,
                                                      w_swz, wkT_swz, wo_swz,
                                                      b_in, b2, gamma, beta, out);
}